// Round 8
// baseline (300.631 us; speedup 1.0000x reference)
//
#include <hip/hip_runtime.h>
#include <hip/hip_bf16.h>

#define TT 2048
#define DD 256
#define KK 4
#define CSZ 1024
#define NROWS 16384
#define TM 16           // rows per block -> 1024 blocks
#define TAU 0.5f
#define MAXC 128

typedef __attribute__((ext_vector_type(8))) short bf16x8;
typedef __attribute__((ext_vector_type(4))) float f32x4;

__device__ __forceinline__ short f2bf(float f) {
    __hip_bfloat16 h = __float2bfloat16(f);
    return (short)__builtin_bit_cast(unsigned short, h);
}
__device__ __forceinline__ unsigned enc32(float f) {
    unsigned u = __builtin_bit_cast(unsigned, f);
    return (u & 0x80000000u) ? ~u : (u | 0x80000000u);
}
__device__ __forceinline__ float dec32(unsigned e) {
    unsigned u = (e & 0x80000000u) ? (e ^ 0x80000000u) : ~e;
    return __builtin_bit_cast(float, u);
}
__device__ __forceinline__ unsigned long long enc_d(double d) {
    unsigned long long u = __double_as_longlong(d);
    return (u & 0x8000000000000000ull) ? ~u : (u | 0x8000000000000000ull);
}

// bf16 copy of codebook, same [k][c][d] layout
__global__ __launch_bounds__(256) void cb_tobf(const float* __restrict__ cb,
                                               short* __restrict__ hi) {
    long e = (long)blockIdx.x * 256 + threadIdx.x;   // over K*CS*D = 1,048,576
    hi[e] = f2bf(cb[e]);
}

// per-entry squared norms (fp64 master + fp32 for the scan)
__global__ __launch_bounds__(256) void cnorm_kernel(const float* __restrict__ cb,
                                                    double* __restrict__ cn_d,
                                                    float* __restrict__ cn_f) {
    int e = blockIdx.x * 256 + threadIdx.x;          // K*CS = 4096
    const float* p = cb + (long)e * DD;
    double s = 0.0;
    for (int d = 0; d < DD; ++d) { double v = (double)p[d]; s += v * v; }
    cn_d[e] = s;
    cn_f[e] = (float)s;
}

#define LOADB(Bv, CNv, ct_) {                                         \
    const int cE_ = seg + (ct_) * 16 + l15;                           \
    const short* bp_ = cbhk + (size_t)cE_ * DD + q8;                  \
    _Pragma("unroll")                                                 \
    for (int kk = 0; kk < 8; ++kk)                                    \
        Bv[kk] = *(const bf16x8*)(bp_ + kk * 32);                     \
    CNv = cnfk[cE_]; }

#define TILE(Bv, CNv, ct_) {                                          \
    f32x4 a0 = {0.f,0.f,0.f,0.f};                                     \
    _Pragma("unroll")                                                 \
    for (int kk = 0; kk < 8; ++kk)                                    \
        a0 = __builtin_amdgcn_mfma_f32_16x16x32_bf16(A0[kk], Bv[kk], a0, 0,0,0); \
    const int cE_ = seg + (ct_) * 16 + l15;                           \
    _Pragma("unroll")                                                 \
    for (int reg = 0; reg < 4; ++reg) {                               \
        float d0_ = fmaf(-2.f, a0[reg], CNv);                         \
        unsigned k0_ = (enc32(d0_) & 0xFFFFFC00u) | (unsigned)cE_;    \
        unsigned m0_ = (bA0[reg] > k0_) ? bA0[reg] : k0_;             \
        bA0[reg] = (bA0[reg] < k0_) ? bA0[reg] : k0_;                 \
        bA1[reg] = (bA1[reg] < m0_) ? bA1[reg] : m0_;                 \
    } }

__global__ __launch_bounds__(256, 4) void rvq_kernel(const float* __restrict__ z,
                                                  const float* __restrict__ cb,
                                                  const short* __restrict__ cb_hi,
                                                  const double* __restrict__ cn_d,
                                                  const float* __restrict__ cn_f,
                                                  int* __restrict__ idx_ws,
                                                  float* __restrict__ out) {
    __shared__ double res_d[TM][DD + 2];             // 33 KB fp64 master residual
    __shared__ unsigned wrowmin[4][TM];
    __shared__ int cand[MAXC];
    __shared__ unsigned long long rowkey[2][TM];     // double-buffered per stage
    __shared__ int ncand;

    const int tid = threadIdx.x;
    const int l   = tid & 63;        // lane
    const int wv  = tid >> 6;        // wave 0..3
    const int l15 = l & 15;
    const int q   = l >> 4;          // quarter 0..3
    const int q8  = q * 8;
    const int row0 = blockIdx.x * TM;
    const int seg  = wv * 256;       // this wave's codebook segment

    // ---- init: z -> fp64 residual; rowkey/ncand ----
#pragma unroll
    for (int r = 0; r < TM; ++r)
        res_d[r][tid] = (double)z[(size_t)(row0 + r) * DD + tid];
    if (tid < TM) { rowkey[0][tid] = ~0ull; rowkey[1][tid] = ~0ull; }
    if (tid == 0) ncand = 0;
    __syncthreads();

    for (int k = 0; k < KK; ++k) {
        const int kb = k & 1;
        // ---- A fragments from fp64 residual (row = l15) ----
        bf16x8 A0[8];
#pragma unroll
        for (int kk = 0; kk < 8; ++kk) {
            const double* r0 = &res_d[l15][kk * 32 + q8];
#pragma unroll
            for (int j = 0; j < 8; ++j)
                A0[kk][j] = f2bf((float)r0[j]);
        }

        // ---- MFMA scan over this wave's 256 entries, double-buffered ----
        const short* __restrict__ cbhk = cb_hi + (size_t)k * CSZ * DD;
        const float* __restrict__ cnfk = cn_f + k * CSZ;
        unsigned bA0[4] = {~0u,~0u,~0u,~0u}, bA1[4] = {~0u,~0u,~0u,~0u};

        bf16x8 Bp[8], Bq[8];
        float cnP, cnQ;
        LOADB(Bp, cnP, 0);
        for (int ct2 = 0; ct2 < 8; ++ct2) {
            LOADB(Bq, cnQ, 2 * ct2 + 1);
            TILE(Bp, cnP, 2 * ct2);
            if (ct2 < 7) LOADB(Bp, cnP, 2 * ct2 + 2);
            TILE(Bq, cnQ, 2 * ct2 + 1);
        }

        // ---- per-wave row min over the 16 lanes of each quarter ----
#pragma unroll
        for (int reg = 0; reg < 4; ++reg) {
            unsigned m = bA0[reg];
            m = min(m, (unsigned)__shfl_xor((int)m, 1, 64));
            m = min(m, (unsigned)__shfl_xor((int)m, 2, 64));
            m = min(m, (unsigned)__shfl_xor((int)m, 4, 64));
            m = min(m, (unsigned)__shfl_xor((int)m, 8, 64));
            if (l15 == 0) wrowmin[wv][q * 4 + reg] = m;
        }
        __syncthreads();                                   // B1: wrowmin visible

        // ---- capture: block min computed inline; best+2nd per lane within TAU ----
#pragma unroll
        for (int reg = 0; reg < 4; ++reg) {
            const int row = q * 4 + reg;
            unsigned rk = min(min(wrowmin[0][row], wrowmin[1][row]),
                              min(wrowmin[2][row], wrowmin[3][row]));
            float thrf = dec32(rk | 0x3FFu) + TAU;
            unsigned tkey = (enc32(thrf) & 0xFFFFFC00u) | 0x3FFu;
            if (bA0[reg] <= tkey) {
                int sl = atomicAdd(&ncand, 1);
                if (sl < MAXC) cand[sl] = row | ((int)(bA0[reg] & 0x3FFu) << 16);
            }
            if (bA1[reg] <= tkey) {
                int sl = atomicAdd(&ncand, 1);
                if (sl < MAXC) cand[sl] = row | ((int)(bA1[reg] & 0x3FFu) << 16);
            }
        }
        __syncthreads();                                   // B2: cand/ncand visible

        // ---- fp64 refine: one candidate per wave, 64-lane dot, atomicMin key ----
        const int nc = (ncand < MAXC) ? ncand : MAXC;
        const float* __restrict__ cbk   = cb + (size_t)k * CSZ * DD;
        const double* __restrict__ cndk = cn_d + k * CSZ;
        for (int i = wv; i < nc; i += 4) {
            int rc  = cand[i];
            int row = rc & 0xFFFF;
            int c   = rc >> 16;
            const float* crow = cbk + (size_t)c * DD;
            double p = 0.0;
#pragma unroll
            for (int j = 0; j < 4; ++j)
                p += res_d[row][4 * l + j] * (double)crow[4 * l + j];
#pragma unroll
            for (int off = 32; off > 0; off >>= 1)
                p += __shfl_xor(p, off, 64);
            if (l == 0) {
                double dist = cndk[c] - 2.0 * p;
                unsigned long long key =
                    (enc_d(dist) & 0xFFFFFFFFFFFFFC00ull) | (unsigned long long)c;
                atomicMin(&rowkey[kb][row], key);
            }
        }
        __syncthreads();                                   // B3: rowkey final

        // ---- idx write + residual update + next-stage resets ----
        if (tid < TM)
            idx_ws[(size_t)(row0 + tid) * KK + k] = (int)(rowkey[kb][tid] & 1023ull);
#pragma unroll
        for (int r = 0; r < TM; ++r) {
            int c = (int)(rowkey[kb][r] & 1023ull);        // broadcast LDS read
            double qv = (double)cbk[(size_t)c * DD + tid];
            double rd = res_d[r][tid];
            double s  = qv - rd;       // stop_gradient(q - residual)
            double zq = rd + s;        // z_q value
            res_d[r][tid] = rd - zq;   // next residual
        }
        if (tid < TM) rowkey[kb ^ 1][tid] = ~0ull;         // reset other buffer
        if (tid == 0) ncand = 0;
        __syncthreads();                                   // B4: res_d ready
    }

    // ---- z_q_final = z - residual_final (f32 out, chunk 0) ----
#pragma unroll
    for (int r = 0; r < TM; ++r) {
        size_t o = (size_t)(row0 + r) * DD + tid;
        out[o] = (float)((double)z[o] - res_d[r][tid]);
    }
}

// index writer: chunk 1, float32 values
__global__ __launch_bounds__(256) void idx_write(const int* __restrict__ idx_ws,
                                                 float* __restrict__ out) {
    int i = blockIdx.x * 256 + threadIdx.x;          // < NROWS*KK = 65536
    out[(long)NROWS * DD + i] = (float)idx_ws[i];
}

extern "C" void kernel_launch(void* const* d_in, const int* in_sizes, int n_in,
                              void* d_out, int out_size, void* d_ws, size_t ws_size,
                              hipStream_t stream) {
    (void)in_sizes; (void)n_in; (void)out_size; (void)ws_size;
    const float* z  = (const float*)d_in[0];
    const float* cb = (const float*)d_in[1];

    char* ws = (char*)d_ws;
    short*  cb_hi = (short*)ws;                                   // 2 MB
    double* cn_d  = (double*)(ws + (size_t)2 * 1024 * 1024);      // 32 KB
    float*  cn_f  = (float*)(ws + (size_t)2 * 1024 * 1024 + 32 * 1024);  // 16 KB
    int*    idxs  = (int*)(ws + (size_t)2 * 1024 * 1024 + 48 * 1024);    // 256 KB
    float* out = (float*)d_out;

    cb_tobf<<<(KK * CSZ * DD) / 256, 256, 0, stream>>>(cb, cb_hi);
    cnorm_kernel<<<(KK * CSZ) / 256, 256, 0, stream>>>(cb, cn_d, cn_f);
    rvq_kernel<<<NROWS / TM, 256, 0, stream>>>(z, cb, cb_hi, cn_d, cn_f, idxs, out);
    idx_write<<<(NROWS * KK) / 256, 256, 0, stream>>>(idxs, out);
}

// Round 9
// 163.755 us; speedup vs baseline: 1.8359x; 1.8359x over previous
//
#include <hip/hip_runtime.h>
#include <hip/hip_bf16.h>

#define DD 256
#define KK 4
#define CSZ 1024
#define NROWS 16384
#define TM 64           // rows per block -> 256 blocks, 1 per CU
#define TAU 0.5f
#define MAXC 192

typedef __attribute__((ext_vector_type(8))) short bf16x8;
typedef __attribute__((ext_vector_type(4))) float f32x4;

__device__ __forceinline__ short f2bf(float f) {
    __hip_bfloat16 h = __float2bfloat16(f);
    return (short)__builtin_bit_cast(unsigned short, h);
}
__device__ __forceinline__ unsigned enc32(float f) {
    unsigned u = __builtin_bit_cast(unsigned, f);
    return (u & 0x80000000u) ? ~u : (u | 0x80000000u);
}
__device__ __forceinline__ float dec32(unsigned e) {
    unsigned u = (e & 0x80000000u) ? (e ^ 0x80000000u) : ~e;
    return __builtin_bit_cast(float, u);
}
__device__ __forceinline__ unsigned long long enc_d(double d) {
    unsigned long long u = __double_as_longlong(d);
    return (u & 0x8000000000000000ull) ? ~u : (u | 0x8000000000000000ull);
}

// bf16 copy of codebook, same [k][c][d] layout
__global__ __launch_bounds__(256) void cb_tobf(const float* __restrict__ cb,
                                               short* __restrict__ hi) {
    long e = (long)blockIdx.x * 256 + threadIdx.x;   // over K*CS*D = 1,048,576
    hi[e] = f2bf(cb[e]);
}

// per-entry squared norms, wave-per-entry (coalesced)
__global__ __launch_bounds__(256) void cnorm_kernel(const float* __restrict__ cb,
                                                    double* __restrict__ cn_d,
                                                    float* __restrict__ cn_f) {
    int wv = threadIdx.x >> 6, l = threadIdx.x & 63;
    int e = blockIdx.x * 4 + wv;                     // grid 1024 -> 4096 entries
    float4 v = *(const float4*)(cb + (size_t)e * DD + l * 4);
    double s = (double)v.x * (double)v.x + (double)v.y * (double)v.y
             + (double)v.z * (double)v.z + (double)v.w * (double)v.w;
#pragma unroll
    for (int off = 32; off > 0; off >>= 1) s += __shfl_xor(s, off, 64);
    if (l == 0) { cn_d[e] = s; cn_f[e] = (float)s; }
}

#define LOADB(Bv, CNv, ct_) {                                         \
    const int cE_ = seg + (ct_) * 16 + l15;                           \
    const short* bp_ = cbhk + (size_t)cE_ * DD + q8;                  \
    _Pragma("unroll")                                                 \
    for (int kk = 0; kk < 8; ++kk)                                    \
        Bv[kk] = *(const bf16x8*)(bp_ + kk * 32);                     \
    CNv = cnfk[cE_]; }

#define TILE4(Bv, CNv, ct_) {                                         \
    f32x4 ac0 = {0.f,0.f,0.f,0.f}, ac1 = {0.f,0.f,0.f,0.f};           \
    f32x4 ac2 = {0.f,0.f,0.f,0.f}, ac3 = {0.f,0.f,0.f,0.f};           \
    _Pragma("unroll")                                                 \
    for (int kk = 0; kk < 8; ++kk) {                                  \
        ac0 = __builtin_amdgcn_mfma_f32_16x16x32_bf16(A[0][kk], Bv[kk], ac0, 0,0,0); \
        ac1 = __builtin_amdgcn_mfma_f32_16x16x32_bf16(A[1][kk], Bv[kk], ac1, 0,0,0); \
        ac2 = __builtin_amdgcn_mfma_f32_16x16x32_bf16(A[2][kk], Bv[kk], ac2, 0,0,0); \
        ac3 = __builtin_amdgcn_mfma_f32_16x16x32_bf16(A[3][kk], Bv[kk], ac3, 0,0,0); \
    }                                                                 \
    const int cE_ = seg + (ct_) * 16 + l15;                           \
    _Pragma("unroll")                                                 \
    for (int reg = 0; reg < 4; ++reg) {                               \
        float dd0 = fmaf(-2.f, ac0[reg], CNv);                        \
        unsigned kx = (enc32(dd0) & 0xFFFFFC00u) | (unsigned)cE_;     \
        unsigned mx = (b0[0][reg] > kx) ? b0[0][reg] : kx;            \
        b0[0][reg] = (b0[0][reg] < kx) ? b0[0][reg] : kx;             \
        b1[0][reg] = (b1[0][reg] < mx) ? b1[0][reg] : mx;             \
        float dd1 = fmaf(-2.f, ac1[reg], CNv);                        \
        kx = (enc32(dd1) & 0xFFFFFC00u) | (unsigned)cE_;              \
        mx = (b0[1][reg] > kx) ? b0[1][reg] : kx;                     \
        b0[1][reg] = (b0[1][reg] < kx) ? b0[1][reg] : kx;             \
        b1[1][reg] = (b1[1][reg] < mx) ? b1[1][reg] : mx;             \
        float dd2 = fmaf(-2.f, ac2[reg], CNv);                        \
        kx = (enc32(dd2) & 0xFFFFFC00u) | (unsigned)cE_;              \
        mx = (b0[2][reg] > kx) ? b0[2][reg] : kx;                     \
        b0[2][reg] = (b0[2][reg] < kx) ? b0[2][reg] : kx;             \
        b1[2][reg] = (b1[2][reg] < mx) ? b1[2][reg] : mx;             \
        float dd3 = fmaf(-2.f, ac3[reg], CNv);                        \
        kx = (enc32(dd3) & 0xFFFFFC00u) | (unsigned)cE_;              \
        mx = (b0[3][reg] > kx) ? b0[3][reg] : kx;                     \
        b0[3][reg] = (b0[3][reg] < kx) ? b0[3][reg] : kx;             \
        b1[3][reg] = (b1[3][reg] < mx) ? b1[3][reg] : mx;             \
    } }

__global__ __launch_bounds__(256, 1) void rvq_kernel(const float* __restrict__ z,
                                                  const float* __restrict__ cb,
                                                  const short* __restrict__ cb_hi,
                                                  const double* __restrict__ cn_d,
                                                  const float* __restrict__ cn_f,
                                                  int* __restrict__ idx_ws,
                                                  float* __restrict__ out) {
    __shared__ double res_d[TM][DD + 1];             // 131.6 KB fp64 master residual
    __shared__ unsigned wrowmin[4][TM];
    __shared__ int cand[MAXC];
    __shared__ unsigned long long rowkey[2][TM];     // double-buffered per stage
    __shared__ int ncand;

    const int tid = threadIdx.x;
    const int l   = tid & 63;        // lane
    const int wv  = tid >> 6;        // wave 0..3
    const int l15 = l & 15;
    const int q   = l >> 4;          // quarter 0..3
    const int q8  = q * 8;
    const int row0 = blockIdx.x * TM;
    const int seg  = wv * 256;       // this wave's codebook segment

    // ---- init: z -> fp64 residual; rowkey/ncand ----
#pragma unroll 4
    for (int r = 0; r < TM; ++r)
        res_d[r][tid] = (double)z[(size_t)(row0 + r) * DD + tid];
    if (tid < TM) { rowkey[0][tid] = ~0ull; rowkey[1][tid] = ~0ull; }
    if (tid == 0) ncand = 0;
    __syncthreads();

    for (int k = 0; k < KK; ++k) {
        const int kb = k & 1;
        // ---- A fragments for 4 row-tiles (row = rt*16 + l15) ----
        bf16x8 A[4][8];
#pragma unroll
        for (int rt = 0; rt < 4; ++rt)
#pragma unroll
            for (int kk = 0; kk < 8; ++kk) {
                const double* rp = &res_d[rt * 16 + l15][kk * 32 + q8];
#pragma unroll
                for (int j = 0; j < 8; ++j)
                    A[rt][kk][j] = f2bf((float)rp[j]);
            }

        // ---- MFMA scan over this wave's 256 entries, double-buffered ----
        const short* __restrict__ cbhk = cb_hi + (size_t)k * CSZ * DD;
        const float* __restrict__ cnfk = cn_f + k * CSZ;
        unsigned b0[4][4], b1[4][4];
#pragma unroll
        for (int rt = 0; rt < 4; ++rt)
#pragma unroll
            for (int reg = 0; reg < 4; ++reg) { b0[rt][reg] = ~0u; b1[rt][reg] = ~0u; }

        bf16x8 Bp[8], Bq[8];
        float cnP, cnQ;
        LOADB(Bp, cnP, 0);
        for (int ct2 = 0; ct2 < 8; ++ct2) {
            LOADB(Bq, cnQ, 2 * ct2 + 1);
            TILE4(Bp, cnP, 2 * ct2);
            if (ct2 < 7) LOADB(Bp, cnP, 2 * ct2 + 2);
            TILE4(Bq, cnQ, 2 * ct2 + 1);
        }

        // ---- per-wave row mins (16-lane groups) ----
#pragma unroll
        for (int rt = 0; rt < 4; ++rt)
#pragma unroll
            for (int reg = 0; reg < 4; ++reg) {
                unsigned m = b0[rt][reg];
                m = min(m, (unsigned)__shfl_xor((int)m, 1, 64));
                m = min(m, (unsigned)__shfl_xor((int)m, 2, 64));
                m = min(m, (unsigned)__shfl_xor((int)m, 4, 64));
                m = min(m, (unsigned)__shfl_xor((int)m, 8, 64));
                if (l15 == 0) wrowmin[wv][rt * 16 + q * 4 + reg] = m;
            }
        __syncthreads();

        // ---- capture: block min inline; best+2nd per lane-slot within TAU ----
#pragma unroll
        for (int rt = 0; rt < 4; ++rt)
#pragma unroll
            for (int reg = 0; reg < 4; ++reg) {
                const int row = rt * 16 + q * 4 + reg;
                unsigned rk = min(min(wrowmin[0][row], wrowmin[1][row]),
                                  min(wrowmin[2][row], wrowmin[3][row]));
                float thrf = dec32(rk | 0x3FFu) + TAU;
                unsigned tkey = (enc32(thrf) & 0xFFFFFC00u) | 0x3FFu;
                if (b0[rt][reg] <= tkey) {
                    int sl = atomicAdd(&ncand, 1);
                    if (sl < MAXC) cand[sl] = row | ((int)(b0[rt][reg] & 0x3FFu) << 16);
                }
                if (b1[rt][reg] <= tkey) {
                    int sl = atomicAdd(&ncand, 1);
                    if (sl < MAXC) cand[sl] = row | ((int)(b1[rt][reg] & 0x3FFu) << 16);
                }
            }
        __syncthreads();

        // ---- fp64 refine: 16-lane groups, one candidate each, strided ----
        const int nc = (ncand < MAXC) ? ncand : MAXC;
        const float* __restrict__ cbk   = cb + (size_t)k * CSZ * DD;
        const double* __restrict__ cndk = cn_d + k * CSZ;
        const int g = tid >> 4;                      // group 0..15
        for (int i = g; i < nc; i += 16) {
            int rc  = cand[i];
            int row = rc & 0xFFFF;
            int c   = rc >> 16;
            const float* crow = cbk + (size_t)c * DD;
            double p = 0.0;
#pragma unroll
            for (int ii = 0; ii < 16; ++ii)
                p += res_d[row][ii * 16 + l15] * (double)crow[ii * 16 + l15];
            p += __shfl_xor(p, 1, 64);
            p += __shfl_xor(p, 2, 64);
            p += __shfl_xor(p, 4, 64);
            p += __shfl_xor(p, 8, 64);
            if (l15 == 0) {
                double dist = cndk[c] - 2.0 * p;
                unsigned long long key =
                    (enc_d(dist) & 0xFFFFFFFFFFFFFC00ull) | (unsigned long long)c;
                atomicMin(&rowkey[kb][row], key);
            }
        }
        __syncthreads();

        // ---- idx write + residual update + next-stage resets ----
        if (tid < TM)
            idx_ws[(size_t)(row0 + tid) * KK + k] = (int)(rowkey[kb][tid] & 1023ull);
#pragma unroll 4
        for (int r = 0; r < TM; ++r) {
            int c = (int)(rowkey[kb][r] & 1023ull);  // broadcast LDS read
            double qv = (double)cbk[(size_t)c * DD + tid];
            double rd = res_d[r][tid];
            double s  = qv - rd;       // stop_gradient(q - residual)
            double zq = rd + s;        // z_q value
            res_d[r][tid] = rd - zq;   // next residual
        }
        if (tid < TM) rowkey[kb ^ 1][tid] = ~0ull;
        if (tid == 0) ncand = 0;
        __syncthreads();
    }

    // ---- z_q_final = z - residual_final (f32 out, chunk 0) ----
#pragma unroll 4
    for (int r = 0; r < TM; ++r) {
        size_t o = (size_t)(row0 + r) * DD + tid;
        out[o] = (float)((double)z[o] - res_d[r][tid]);
    }
}

// index writer: chunk 1, float32 values
__global__ __launch_bounds__(256) void idx_write(const int* __restrict__ idx_ws,
                                                 float* __restrict__ out) {
    int i = blockIdx.x * 256 + threadIdx.x;          // < NROWS*KK = 65536
    out[(long)NROWS * DD + i] = (float)idx_ws[i];
}

extern "C" void kernel_launch(void* const* d_in, const int* in_sizes, int n_in,
                              void* d_out, int out_size, void* d_ws, size_t ws_size,
                              hipStream_t stream) {
    (void)in_sizes; (void)n_in; (void)out_size; (void)ws_size;
    const float* z  = (const float*)d_in[0];
    const float* cb = (const float*)d_in[1];

    char* ws = (char*)d_ws;
    short*  cb_hi = (short*)ws;                                   // 2 MB
    double* cn_d  = (double*)(ws + (size_t)2 * 1024 * 1024);      // 32 KB
    float*  cn_f  = (float*)(ws + (size_t)2 * 1024 * 1024 + 32 * 1024);  // 16 KB
    int*    idxs  = (int*)(ws + (size_t)2 * 1024 * 1024 + 48 * 1024);    // 256 KB
    float* out = (float*)d_out;

    cb_tobf<<<(KK * CSZ * DD) / 256, 256, 0, stream>>>(cb, cb_hi);
    cnorm_kernel<<<(KK * CSZ) / 4, 256, 0, stream>>>(cb, cn_d, cn_f);
    rvq_kernel<<<NROWS / TM, 256, 0, stream>>>(z, cb, cb_hi, cn_d, cn_f, idxs, out);
    idx_write<<<(NROWS * KK) / 256, 256, 0, stream>>>(idxs, out);
}